// Round 7
// baseline (60.637 us; speedup 1.0000x reference)
//
#include <hip/hip_runtime.h>
#include <math.h>

constexpr int B_ = 64, Q_ = 900, N_ = 100, C_ = 256;
constexpr float EPSF = 1e-6f;
constexpr float BOX_W = 5.0f, GIOU_W = 2.0f, CLS_W = 1.0f;
constexpr int KP = 15;  // preds per lane: 64 lanes * 15 >= 900
constexpr int K_ = 8;   // candidate depth per column
typedef unsigned long long u64;
typedef unsigned int u32;

__device__ __forceinline__ float giou_f(float px0, float py0, float px1, float py1, float pa,
                                        float tx0, float ty0, float tx1, float ty1, float ta) {
    float ltx = fmaxf(px0, tx0), lty = fmaxf(py0, ty0);
    float rbx = fminf(px1, tx1), rby = fminf(py1, ty1);
    float w = fmaxf(rbx - ltx, 0.0f), h = fmaxf(rby - lty, 0.0f);
    float inter = w * h;
    float uni = pa + ta - inter;
    float iou = inter / (uni + EPSF);
    float ex0 = fminf(px0, tx0), ey0 = fminf(py0, ty0);
    float ex1 = fmaxf(px1, tx1), ey1 = fmaxf(py1, ty1);
    float ew = fmaxf(ex1 - ex0, 0.0f), eh = fmaxf(ey1 - ey0, 0.0f);
    float earea = ew * eh;
    return iou - (earea - uni) / (earea + EPSF);
}

// order-preserving float->uint; key = (ord << 32) | ~q => u64 max == (max value, min index)
__device__ __forceinline__ u32 f2ord(float f) {
    u32 u = __float_as_uint(f);
    return (u & 0x80000000u) ? ~u : (u | 0x80000000u);
}
__device__ __forceinline__ u64 mkkey(float g, int q) {
    return ((u64)f2ord(g) << 32) | (u32)(~(u32)q);
}
__device__ __forceinline__ int keyidx(u64 k) { return (int)(~(u32)k); }

// ---------------- kernel 1: per-column exact top-8 (indices out) ----------------
// 1600 blocks x 256 threads; each wave owns one (b,n) column
__global__ __launch_bounds__(256) void cand_kernel(
    const float* __restrict__ pred_boxes,   // [B,Q,4] cxcywh
    const float* __restrict__ target_boxes, // [B,N,4] xyxy
    u32* __restrict__ cands,                // [B*N*8] pred indices, descending key order
    u32* __restrict__ cnt)                  // completion counter for kernel 2 (zeroed here)
{
    if (blockIdx.x == 0 && threadIdx.x == 0) *cnt = 0u;

    const int blk = blockIdx.x;
    const int b = blk / 25;
    const int wave = threadIdx.x >> 6;
    const int lane = threadIdx.x & 63;
    const int n = (blk % 25) * 4 + wave;
    const int bn = b * N_ + n;

    const float* t = target_boxes + (size_t)bn * 4;
    float tx0 = t[0], ty0 = t[1], tx1 = t[2], ty1 = t[3];
    float ta = (tx1 - tx0) * (ty1 - ty0);

    const float4* pbv = (const float4*)(pred_boxes + (size_t)b * Q_ * 4);

    // per-lane u32 ords (compile-time indexed -> registers)
    u32 ordv[KP];
    #pragma unroll
    for (int k = 0; k < KP; ++k) {
        int q = lane + (k << 6);
        ordv[k] = 0u;
        if (q < Q_) {
            float4 c = pbv[q];
            float x0 = c.x - 0.5f * c.z, y0 = c.y - 0.5f * c.w;
            float x1 = c.x + 0.5f * c.z, y1 = c.y + 0.5f * c.w;
            float pa = (x1 - x0) * (y1 - y0);
            float g = giou_f(x0, y0, x1, y1, pa, tx0, ty0, tx1, ty1, ta);
            ordv[k] = f2ord(g);
        }
    }

    u32 alive = 0x7FFFu;
    u32 o8[K_];
    #pragma unroll
    for (int j = 0; j < K_; ++j) {
        // branchless masked rescan (u32): strict > keeps smallest k (= smallest q) on ties
        u32 bo = 0u; int bk = 0;
        #pragma unroll
        for (int k = 0; k < KP; ++k) {
            bool tk = (((alive >> k) & 1u) != 0u) && (ordv[k] > bo);
            bo = tk ? ordv[k] : bo;
            bk = tk ? k : bk;
        }
        u64 myk = ((u64)bo << 32) | (u32)(~(u32)(lane + (bk << 6)));
        u64 m = myk;
        #pragma unroll
        for (int off = 32; off >= 1; off >>= 1) {
            u64 o = __shfl_xor(m, off);
            if (o > m) m = o;
        }
        if (myk == m) alive &= ~(1u << bk);  // unique winner pops
        o8[j] = (u32)(~(u32)m);
    }
    if (lane == 0) {
        uint4* outp = (uint4*)(cands + (size_t)bn * K_);
        outp[0] = make_uint4(o8[0], o8[1], o8[2], o8[3]);
        outp[1] = make_uint4(o8[4], o8[5], o8[6], o8[7]);
    }
}

// ---- kernel 2: batched prefix-commit resolve + box loss + BCE + last-block finalize ----
__global__ __launch_bounds__(256) void fused_kernel(
    const float* __restrict__ pred_boxes,
    const float* __restrict__ pred_logits,
    const float* __restrict__ target_boxes,
    const int*   __restrict__ target_labels,
    const u32*   __restrict__ cands,
    double* __restrict__ partial,   // [B]
    u32* __restrict__ cnt,
    float* __restrict__ out)
{
    const int b = blockIdx.x;
    const int tid = threadIdx.x;
    const int lane = tid & 63;

    __shared__ float tx0s[N_], ty0s[N_], tx1s[N_], ty1s[N_], tas[N_];
    __shared__ int   s_ms[N_];
    __shared__ int   labs[N_];
    __shared__ u32   s_used[32];
    __shared__ u32   s_claim[1024];
    __shared__ double red[256];
    __shared__ int   s_last;

    #pragma unroll
    for (int i = 0; i < 4; ++i) s_claim[tid + i * 256] = 0u;
    if (tid < 32) s_used[tid] = 0u;
    if (tid < N_) {
        const float* t = target_boxes + (size_t)(b * N_ + tid) * 4;
        float x0 = t[0], y0 = t[1], x1 = t[2], y1 = t[3];
        tx0s[tid] = x0; ty0s[tid] = y0; tx1s[tid] = x1; ty1s[tid] = y1;
        tas[tid] = (x1 - x0) * (y1 - y0);
        labs[tid] = target_labels[b * N_ + tid];
    }

    // transposed candidates: lane L owns column L (A) and column L+64 (B).
    // All 4 waves run the resolve redundantly (identical inputs -> idempotent
    // LDS atomics/writes) so __syncthreads stays legal for the whole block.
    int cA[K_], cB[K_];
    {
        const u32* p = cands + (size_t)(b * N_ + lane) * K_;
        #pragma unroll
        for (int j = 0; j < K_; ++j) cA[j] = (int)p[j];
    }
    #pragma unroll
    for (int j = 0; j < K_; ++j) cB[j] = 0;
    if (lane + 64 < N_) {
        const u32* p = cands + (size_t)(b * N_ + lane + 64) * K_;
        #pragma unroll
        for (int j = 0; j < K_; ++j) cB[j] = (int)p[j];
    }

    const float4* pbv = (const float4*)(pred_boxes + (size_t)b * Q_ * 4);
    bool activeA = true;
    bool activeB = (lane + 64 < N_);
    __syncthreads();

    int round = 1;
    while (__ballot(activeA) | __ballot(activeB)) {
        // --- phase 1: picks = first unused candidate (exact top-8 order) ---
        int pickA = -1, pickB = -1;
        #pragma unroll
        for (int j = 0; j < K_; ++j) {
            int ia = cA[j];
            bool availA = !((s_used[ia >> 5] >> (ia & 31)) & 1u);
            if (pickA < 0 && availA) pickA = ia;
            int ib = cB[j];
            bool availB = !((s_used[ib >> 5] >> (ib & 31)) & 1u);
            if (pickB < 0 && availB) pickB = ib;
        }
        // --- rare fallback: top-8 exhausted -> full masked argmax ---
        u64 fm = __ballot(activeA && pickA < 0);
        while (fm) {
            int c = (int)__builtin_ctzll(fm);
            float tx0 = tx0s[c], ty0 = ty0s[c], tx1 = tx1s[c], ty1 = ty1s[c], ta = tas[c];
            u64 bk = 0ull;
            #pragma unroll
            for (int k = 0; k < KP; ++k) {
                int q = lane + (k << 6);
                if (q < Q_ && !((s_used[q >> 5] >> (q & 31)) & 1u)) {
                    float4 cc = pbv[q];
                    float x0 = cc.x - 0.5f * cc.z, y0 = cc.y - 0.5f * cc.w;
                    float x1 = cc.x + 0.5f * cc.z, y1 = cc.y + 0.5f * cc.w;
                    float pa = (x1 - x0) * (y1 - y0);
                    float g = giou_f(x0, y0, x1, y1, pa, tx0, ty0, tx1, ty1, ta);
                    u64 kk = mkkey(g, q);
                    if (kk > bk) bk = kk;
                }
            }
            #pragma unroll
            for (int off = 32; off >= 1; off >>= 1) {
                u64 o = __shfl_xor(bk, off);
                if (o > bk) bk = o;
            }
            if (lane == c) pickA = keyidx(bk);
            fm &= fm - 1;
        }
        fm = __ballot(activeB && pickB < 0);
        while (fm) {
            int c = (int)__builtin_ctzll(fm);
            int n = c + 64;
            float tx0 = tx0s[n], ty0 = ty0s[n], tx1 = tx1s[n], ty1 = ty1s[n], ta = tas[n];
            u64 bk = 0ull;
            #pragma unroll
            for (int k = 0; k < KP; ++k) {
                int q = lane + (k << 6);
                if (q < Q_ && !((s_used[q >> 5] >> (q & 31)) & 1u)) {
                    float4 cc = pbv[q];
                    float x0 = cc.x - 0.5f * cc.z, y0 = cc.y - 0.5f * cc.w;
                    float x1 = cc.x + 0.5f * cc.z, y1 = cc.y + 0.5f * cc.w;
                    float pa = (x1 - x0) * (y1 - y0);
                    float g = giou_f(x0, y0, x1, y1, pa, tx0, ty0, tx1, ty1, ta);
                    u64 kk = mkkey(g, q);
                    if (kk > bk) bk = kk;
                }
            }
            #pragma unroll
            for (int off = 32; off >= 1; off >>= 1) {
                u64 o = __shfl_xor(bk, off);
                if (o > bk) bk = o;
            }
            if (lane == c) pickB = keyidx(bk);
            fm &= fm - 1;
        }
        // --- phase 2: claims. tag = (round<<16)|(0xFFFF-col) ---
        u32 tagA = ((u32)round << 16) | (0xFFFFu - (u32)lane);
        u32 tagB = ((u32)round << 16) | (0xFFFFu - (u32)(lane + 64));
        if (activeA) atomicMax(&s_claim[pickA], tagA);
        if (activeB) atomicMax(&s_claim[pickB], tagB);
        __syncthreads();
        // --- phase 3: commit winners ---
        if (activeA && s_claim[pickA] == tagA) {
            s_ms[lane] = pickA;
            atomicOr(&s_used[pickA >> 5], 1u << (pickA & 31));
            activeA = false;
        }
        if (activeB && s_claim[pickB] == tagB) {
            s_ms[lane + 64] = pickB;
            atomicOr(&s_used[pickB >> 5], 1u << (pickB & 31));
            activeB = false;
        }
        __syncthreads();
        ++round;
    }

    double acc = 0.0;

    // box losses: one target per thread (tid < 100)
    if (tid < N_) {
        int q = s_ms[tid];
        float4 c = pbv[q];
        float tx0 = tx0s[tid], ty0 = ty0s[tid], tx1 = tx1s[tid], ty1 = ty1s[tid];
        float tcx = (tx0 + tx1) * 0.5f, tcy = (ty0 + ty1) * 0.5f;
        float tw = tx1 - tx0, th = ty1 - ty0;
        float l1 = fabsf(c.x - tcx) + fabsf(c.y - tcy) + fabsf(c.z - tw) + fabsf(c.w - th);
        float x0 = c.x - 0.5f * c.z, y0 = c.y - 0.5f * c.w;
        float x1 = c.x + 0.5f * c.z, y1 = c.y + 0.5f * c.w;
        float pa = (x1 - x0) * (y1 - y0);
        float g = giou_f(x0, y0, x1, y1, pa, tx0, ty0, tx1, ty1, tas[tid]);
        acc += (double)(BOX_W * l1) + (double)(GIOU_W * (1.0f - g));
    }

    // BCE: thread tid owns class tid for all 100 rows (wave reads 256B/row)
    {
        const float* lg = pred_logits + (size_t)b * Q_ * C_ + tid;
        double e0 = 0.0, e1 = 0.0;
        #pragma unroll 4
        for (int n = 0; n < N_; ++n) {
            int q = s_ms[n];
            int lab = labs[n];
            float x = lg[(size_t)q * C_];
            float tt = (tid == lab) ? 1.0f : 0.0f;
            float term = fmaxf(x, 0.0f) - x * tt + log1pf(expf(-fabsf(x)));
            if (n & 1) e1 += (double)term; else e0 += (double)term;
        }
        acc += (double)CLS_W * (e0 + e1);
    }

    red[tid] = acc;
    __syncthreads();
    #pragma unroll
    for (int s = 128; s >= 1; s >>= 1) {
        if (tid < s) red[tid] += red[tid + s];
        __syncthreads();
    }

    // last-block finalize (deterministic: fixed butterfly order regardless of which block runs it)
    if (tid == 0) {
        __hip_atomic_store(&partial[b], red[0], __ATOMIC_RELEASE, __HIP_MEMORY_SCOPE_AGENT);
        u32 old = __hip_atomic_fetch_add(cnt, 1u, __ATOMIC_ACQ_REL, __HIP_MEMORY_SCOPE_AGENT);
        s_last = (old == (u32)(B_ - 1)) ? 1 : 0;
    }
    __syncthreads();
    if (s_last && tid < 64) {
        double v = __hip_atomic_load(&partial[lane], __ATOMIC_ACQUIRE, __HIP_MEMORY_SCOPE_AGENT);
        #pragma unroll
        for (int off = 32; off >= 1; off >>= 1) v += __shfl_xor(v, off);
        if (lane == 0) out[0] = (float)(v / (double)(B_ * N_));
    }
}

extern "C" void kernel_launch(void* const* d_in, const int* in_sizes, int n_in,
                              void* d_out, int out_size, void* d_ws, size_t ws_size,
                              hipStream_t stream) {
    const float* pred_boxes    = (const float*)d_in[0];
    const float* pred_logits   = (const float*)d_in[1];
    const float* target_boxes  = (const float*)d_in[2];
    const int*   target_labels = (const int*)d_in[3];
    float* out = (float*)d_out;

    char* ws = (char*)d_ws;
    u32*    cands   = (u32*)(ws);              // 6400*8*4 = 204800
    double* partial = (double*)(ws + 204800);  // 64*8 = 512
    u32*    cnt     = (u32*)(ws + 205312);     // 4

    hipLaunchKernelGGL(cand_kernel, dim3(1600), dim3(256), 0, stream,
                       pred_boxes, target_boxes, cands, cnt);
    hipLaunchKernelGGL(fused_kernel, dim3(B_), dim3(256), 0, stream,
                       pred_boxes, pred_logits, target_boxes, target_labels,
                       cands, partial, cnt, out);
}